// Round 12
// baseline (2583.142 us; speedup 1.0000x reference)
//
#include <hip/hip_runtime.h>
#include <hip/hip_bf16.h>
#include <stdint.h>

// ---------- types ----------
typedef __attribute__((ext_vector_type(8))) __bf16 bf16x8;
typedef __attribute__((ext_vector_type(4))) float f32x4;
typedef __attribute__((ext_vector_type(8))) unsigned short ushort8;

typedef const void __attribute__((address_space(1))) gv_t;
typedef void __attribute__((address_space(3))) lv_t;

#define GL16(g, l) __builtin_amdgcn_global_load_lds((gv_t*)(g), (lv_t*)(l), 16, 0, 0)

__device__ __forceinline__ unsigned short f2bf(float f) {
    unsigned int u = __float_as_uint(f);
    u += 0x7fffu + ((u >> 16) & 1u);
    return (unsigned short)(u >> 16);
}

// ---------- kernel 1: fused prepass: W int4-qdq -> bf16 ; x f32 -> bf16 ------
__global__ void __launch_bounds__(256) prep(const float* __restrict__ w,
                                            const float* __restrict__ x,
                                            unsigned short* __restrict__ wb,
                                            unsigned short* __restrict__ xb,
                                            int ng_w, int n8_x) {
    int id = blockIdx.x * 256 + threadIdx.x;
    if (id < ng_w) {
        const float4* p = (const float4*)w + (size_t)id * 2;
        float4 v0 = p[0], v1 = p[1];
        float t[8] = {v0.x, v0.y, v0.z, v0.w, v1.x, v1.y, v1.z, v1.w};
        float amax = 0.0f;
#pragma unroll
        for (int j = 0; j < 8; ++j) amax = fmaxf(amax, fabsf(t[j]));
        float scale = fmaxf(amax / 7.0f, 1e-8f);
        ushort8 o;
#pragma unroll
        for (int j = 0; j < 8; ++j) {
            float q = rintf(t[j] / scale);
            q = fminf(fmaxf(q, -7.0f), 7.0f);
            o[j] = f2bf(q * scale);
        }
        *((ushort8*)wb + id) = o;
    } else {
        int i = id - ng_w;
        if (i < n8_x) {
            const float4* p = (const float4*)x + (size_t)i * 2;
            float4 v0 = p[0], v1 = p[1];
            ushort8 o;
            o[0] = f2bf(v0.x); o[1] = f2bf(v0.y); o[2] = f2bf(v0.z); o[3] = f2bf(v0.w);
            o[4] = f2bf(v1.x); o[5] = f2bf(v1.y); o[6] = f2bf(v1.z); o[7] = f2bf(v1.w);
            *((ushort8*)xb + i) = o;
        }
    }
}

// ---------- kernel 2: 256x256 ANTI-PHASE bf16 GEMM ---------------------------
// 8 waves in 2 groups (G0 = M rows 0-127, G1 = rows 128-255). Per K-tile,
// 4 windows; the groups alternate roles so that in EVERY window 4 waves use
// the LDS port (12 ds_read_b128 each) while the other 4 run their 32-MFMA
// cluster -> port and matrix pipe both busy (window = max, not sum).
// Each group stages one half-tile (4 gload_lds) per read window, gated VM(4)
// (VM(0) at tail). Cross-group read certification = other group's gate one
// window earlier + the shared barrier (audited per window).
#define BM 256
#define BN 256
#define BK 64

#define BAR_() asm volatile("s_barrier" ::: "memory")
#define VM_(n) asm volatile("s_waitcnt vmcnt(" #n ")" ::: "memory")
#define VMG(st) { if (st) VM_(4); else VM_(0); }

// stage this group's A-half of the K-tile at column kk into buf b (4 loads)
#define STAGE_AH(b, kk)                                                        \
    { _Pragma("unroll")                                                        \
      for (int j = 0; j < 4; ++j)                                              \
          GL16(gA + (size_t)(G * 128 + j * 32 + wc * 8 + (ln >> 3)) * K        \
                   + (kk) + schunk,                                            \
               &sA[b][G][(j * 32 + wc * 8) * BK]); }

// stage this group's B-half (n ≡ G*32 mod 64, interleaved layout) into buf b
#define STAGE_BH(b, kk)                                                        \
    { _Pragma("unroll")                                                        \
      for (int j = 0; j < 4; ++j)                                              \
          GL16(gB + (size_t)(j * 64 + G * 32 + wc * 8 + (ln >> 3)) * K         \
                   + (kk) + schunk,                                            \
               &sB[b][G][(j * 32 + wc * 8) * BK]); }

// read one k-substep: 8 A-frags (own half) + 4 B-frags (2 per B-half)
#define READ_SUB(b, E)                                                         \
    { _Pragma("unroll")                                                        \
      for (int mi = 0; mi < 8; ++mi)                                           \
          af[mi] = *(const bf16x8*)&sA[b][G][(mi * 16 + lr) * BK + (E)];       \
      _Pragma("unroll")                                                        \
      for (int j = 0; j < 4; ++j)                                              \
          bf[j] = *(const bf16x8*)                                             \
              &sB[b][j >> 1][(wc * 32 + (j & 1) * 16 + lr) * BK + (E)]; }

#define MFMA_SUB()                                                             \
    { __builtin_amdgcn_s_setprio(1);                                           \
      _Pragma("unroll")                                                        \
      for (int mi = 0; mi < 8; ++mi)                                           \
          _Pragma("unroll")                                                    \
          for (int j = 0; j < 4; ++j)                                          \
              acc[mi][j] = __builtin_amdgcn_mfma_f32_16x16x32_bf16(            \
                  af[mi], bf[j], acc[mi][j], 0, 0, 0);                         \
      __builtin_amdgcn_s_setprio(0); }

__global__ void __launch_bounds__(512, 2)
gemmAP(const unsigned short* __restrict__ A,   // [M][K] bf16 bits (x)
       const unsigned short* __restrict__ B,   // [N][K] bf16 bits (w_deq)
       const float* __restrict__ bias,
       float* __restrict__ C,
       int M, int N, int K) {
    __shared__ unsigned short sA[2][2][128 * BK];   // 64 KiB
    __shared__ unsigned short sB[2][2][128 * BK];   // 64 KiB

    const int t  = threadIdx.x;
    const int ws = __builtin_amdgcn_readfirstlane(t) >> 6;   // scalar wave id
    const int G  = ws >> 2;        // group: 0 = rows 0-127, 1 = rows 128-255
    const int wc = ws & 3;         // wave N index (64 cols)
    const int ln = t & 63;
    const int lr = ln & 15;
    const int lk = ln >> 4;

    // T1: bijective XCD swizzle (gridDim.x % 8 == 0 here)
    const int nbn = N / BN;
    const int bid = blockIdx.x;
    const int swz = ((int)gridDim.x & 7) ? bid
                  : ((bid & 7) * ((int)gridDim.x >> 3) + (bid >> 3));
    const int m0 = (swz / nbn) * BM;
    const int n0 = (swz % nbn) * BN;

    const unsigned short* gA = A + (size_t)m0 * K;
    const unsigned short* gB = B + (size_t)n0 * K;

    // staging: lane covers row (ln>>3) within its wave's 8-row stripe,
    // chunk (ln&7) pre-swizzled by row&7 (= ln>>3); LDS dest linear (rule #21)
    const int schunk = (((ln & 7) ^ (ln >> 3)) << 3);   // elements

    // swizzled ds_read element offsets per k-substep (proven 0-conflict)
    const int e0 = ((lk ^ (lr & 7)) << 3);
    const int e1 = (((4 + lk) ^ (lr & 7)) << 3);

    f32x4 acc[8][4];
#pragma unroll
    for (int i = 0; i < 8; ++i)
#pragma unroll
        for (int j = 0; j < 4; ++j)
            acc[i][j] = (f32x4)(0.0f);

    bf16x8 af[8], bf[4];

    const int NT = K / BK;   // 64

    // prologue: each group stages its two halves of tile 0; full drain
    STAGE_AH(0, 0);
    STAGE_BH(0, 0);
    VM_(0);
    BAR_();

    for (int T = 0; T < NT; ++T) {
        const int b  = T & 1;
        const int nb = b ^ 1;
        const int kn = (T + 1) * BK;
        const bool st = (T + 1 < NT);

        // window 4T+0: G0 stage Ah0(T+1) + read ks0 | G1 MFMA ks1(T-1)
        if (G == 0) {
            if (st) STAGE_AH(nb, kn);
            VMG(st);
            READ_SUB(b, e0);
        } else {
            if (T > 0) MFMA_SUB();
        }
        BAR_();

        // window 4T+1: G0 MFMA ks0 | G1 stage Bh1(T+1) + read ks0
        if (G == 0) {
            MFMA_SUB();
        } else {
            if (st) STAGE_BH(nb, kn);
            VMG(st);
            READ_SUB(b, e0);
        }
        BAR_();

        // window 4T+2: G0 stage Bh0(T+1) + read ks1 | G1 MFMA ks0
        if (G == 0) {
            if (st) STAGE_BH(nb, kn);
            VMG(st);
            READ_SUB(b, e1);
        } else {
            MFMA_SUB();
        }
        BAR_();

        // window 4T+3: G0 MFMA ks1 | G1 stage Ah1(T+1) + read ks1
        if (G == 0) {
            MFMA_SUB();
        } else {
            if (st) STAGE_AH(nb, kn);
            VMG(st);
            READ_SUB(b, e1);
        }
        BAR_();
    }
    // tail window: G1's last MFMA (ks1 of tile NT-1)
    if (G == 1) MFMA_SUB();
    BAR_();

    // epilogue: C/D layout col = lane&15, row = (lane>>4)*4 + reg
#pragma unroll
    for (int j = 0; j < 4; ++j) {
        const int n = n0 + wc * 64 + (j >> 1) * 32 + (j & 1) * 16 + lr;
        const float bv = bias[n];
#pragma unroll
        for (int mi = 0; mi < 8; ++mi) {
            const int m = m0 + G * 128 + mi * 16 + lk * 4;
            f32x4 v = acc[mi][j];
            C[(size_t)(m + 0) * N + n] = v[0] + bv;
            C[(size_t)(m + 1) * N + n] = v[1] + bv;
            C[(size_t)(m + 2) * N + n] = v[2] + bv;
            C[(size_t)(m + 3) * N + n] = v[3] + bv;
        }
    }
}

// ---------- launcher ----------
extern "C" void kernel_launch(void* const* d_in, const int* in_sizes, int n_in,
                              void* d_out, int out_size, void* d_ws, size_t ws_size,
                              hipStream_t stream) {
    const float* x    = (const float*)d_in[0];
    const float* wgt  = (const float*)d_in[1];
    const float* bias = (const float*)d_in[2];
    float* out        = (float*)d_out;

    const int dout = in_sizes[2];            // 4096
    const int din  = in_sizes[1] / dout;     // 4096
    const int M    = in_sizes[0] / din;      // 8192
    const int N    = dout, K = din;

    unsigned short* xb = (unsigned short*)d_ws;          // [M][K] bf16 bits
    unsigned short* wb = xb + (size_t)M * K;             // [N][K] bf16 bits

    const int ng_w = (N * K) / 8;
    const int n8_x = (M * K) / 8;
    prep<<<(ng_w + n8_x + 255) / 256, 256, 0, stream>>>(wgt, x, wb, xb, ng_w, n8_x);

    const int nwg = (M / BM) * (N / BN);     // 512, % 8 == 0
    gemmAP<<<nwg, 512, 0, stream>>>(xb, wb, bias, out, M, N, K);
}

// Round 13
// 297.727 us; speedup vs baseline: 8.6762x; 8.6762x over previous
//
#include <hip/hip_runtime.h>
#include <hip/hip_bf16.h>
#include <stdint.h>

// ---------- types ----------
typedef __attribute__((ext_vector_type(8))) __bf16 bf16x8;
typedef __attribute__((ext_vector_type(4))) float f32x4;
typedef __attribute__((ext_vector_type(8))) unsigned short ushort8;

typedef const void __attribute__((address_space(1))) gv_t;
typedef void __attribute__((address_space(3))) lv_t;

#define GL16(g, l) __builtin_amdgcn_global_load_lds((gv_t*)(g), (lv_t*)(l), 16, 0, 0)

// f32 -> bf16 bits, round-to-nearest-even
__device__ __forceinline__ unsigned short f2bf(float f) {
    unsigned int u = __float_as_uint(f);
    u += 0x7fffu + ((u >> 16) & 1u);
    return (unsigned short)(u >> 16);
}

// ---------- kernel 1: per-group int4 quant-dequant of W -> bf16 bits ----------
__global__ void __launch_bounds__(256) qdq_weight(const float* __restrict__ w,
                                                  unsigned short* __restrict__ wb,
                                                  int n_groups) {
    int g = blockIdx.x * 256 + threadIdx.x;
    if (g >= n_groups) return;
    const float4* p = (const float4*)w + (size_t)g * 2;
    float4 v0 = p[0], v1 = p[1];
    float t[8] = {v0.x, v0.y, v0.z, v0.w, v1.x, v1.y, v1.z, v1.w};
    float amax = 0.0f;
#pragma unroll
    for (int j = 0; j < 8; ++j) amax = fmaxf(amax, fabsf(t[j]));
    float scale = fmaxf(amax / 7.0f, 1e-8f);
    ushort8 o;
#pragma unroll
    for (int j = 0; j < 8; ++j) {
        float q = rintf(t[j] / scale);
        q = fminf(fmaxf(q, -7.0f), 7.0f);
        o[j] = f2bf(q * scale);
    }
    *((ushort8*)wb + g) = o;
}

// ---------- kernel 2: f32 -> bf16 cast of x ----------
__global__ void __launch_bounds__(256) cvt_bf16(const float* __restrict__ x,
                                                unsigned short* __restrict__ xb,
                                                int n8) {
    int i = blockIdx.x * 256 + threadIdx.x;
    if (i >= n8) return;
    const float4* p = (const float4*)x + (size_t)i * 2;
    float4 v0 = p[0], v1 = p[1];
    ushort8 o;
    o[0] = f2bf(v0.x); o[1] = f2bf(v0.y); o[2] = f2bf(v0.z); o[3] = f2bf(v0.w);
    o[4] = f2bf(v1.x); o[5] = f2bf(v1.y); o[6] = f2bf(v1.z); o[7] = f2bf(v1.w);
    *((ushort8*)xb + i) = o;
}

// ---------- kernel 3: 256x256 8-wave 8-phase bf16 GEMM (best measured) --------
// Session best (R6): 267-270 us GEMM, MfmaUtil ~44%, 0 bank conflicts.
// Phase = { ds_reads | 1 half-tile stage | [lgkm hint] ; s_barrier ;
//           lgkmcnt(0) ; sched_barrier(0) ; setprio(1) 16xMFMA setprio(0) ;
//           s_barrier }   with counted vmcnt(4) only at phases 4/8.
#define BM 256
#define BN 256
#define BK 64

#define MFMA_Q(qm, qn, AF, BF)                                                 \
    __builtin_amdgcn_s_setprio(1);                                             \
    _Pragma("unroll")                                                          \
    for (int mi = 0; mi < 4; ++mi)                                             \
        _Pragma("unroll")                                                      \
        for (int ni = 0; ni < 2; ++ni)                                         \
            _Pragma("unroll")                                                  \
            for (int ks = 0; ks < 2; ++ks)                                     \
                acc[(qm) * 4 + mi][(qn) * 2 + ni] =                            \
                    __builtin_amdgcn_mfma_f32_16x16x32_bf16(                   \
                        AF[mi][ks], BF[ni][ks],                                \
                        acc[(qm) * 4 + mi][(qn) * 2 + ni], 0, 0, 0);           \
    __builtin_amdgcn_s_setprio(0);

#define STAGE_A(b, h, kk)                                                      \
    {                                                                          \
        GL16(gA + (size_t)((h) * 64 + srow) * K + (kk) + schunk,               \
             &sA[b][h][0] + sldso);                                            \
        GL16(gA + (size_t)((h) * 64 + 128 + srow) * K + (kk) + schunk,         \
             &sA[b][h][64 * BK] + sldso);                                      \
    }
#define STAGE_B(b, h, kk)                                                      \
    {                                                                          \
        GL16(gB + (size_t)((h) * 32 + brow) * K + (kk) + schunk,               \
             &sB[b][h][0] + sldso);                                            \
        GL16(gB + (size_t)((h) * 32 + 128 + brow) * K + (kk) + schunk,         \
             &sB[b][h][64 * BK] + sldso);                                      \
    }

#define READ_A(dst, b, h)                                                      \
    _Pragma("unroll")                                                          \
    for (int mi = 0; mi < 4; ++mi) {                                           \
        const int s_ = (wr * 64 + mi * 16 + lr) * BK;                          \
        dst[mi][0] = *(const bf16x8*)&sA[b][h][s_ + e0];                       \
        dst[mi][1] = *(const bf16x8*)&sA[b][h][s_ + e1];                       \
    }
#define READ_B(dst, b, h)                                                      \
    _Pragma("unroll")                                                          \
    for (int ni = 0; ni < 2; ++ni) {                                           \
        const int s_ = (bcol + ni * 16 + lr) * BK;                             \
        dst[ni][0] = *(const bf16x8*)&sB[b][h][s_ + e0];                       \
        dst[ni][1] = *(const bf16x8*)&sB[b][h][s_ + e1];                       \
    }

#define BAR_()     asm volatile("s_barrier" ::: "memory")
#define VM_(n)     asm volatile("s_waitcnt vmcnt(" #n ")" ::: "memory")
#define LGKM_(n)   asm volatile("s_waitcnt lgkmcnt(" #n ")" ::: "memory")
#define SCHEDBAR() __builtin_amdgcn_sched_barrier(0)

#define PHASE(RDS, STG, QM, QN, AF, BF, HINT, VMQ)                             \
    {                                                                          \
        RDS;                                                                   \
        STG;                                                                   \
        HINT;                                                                  \
        BAR_();                                                                \
        LGKM_(0);                                                              \
        SCHEDBAR();                                                            \
        MFMA_Q(QM, QN, AF, BF);                                                \
        VMQ;                                                                   \
        BAR_();                                                                \
    }

__global__ void __launch_bounds__(512, 2)
gemm256(const unsigned short* __restrict__ A,   // [M][K] bf16 bits (x)
        const unsigned short* __restrict__ B,   // [N][K] bf16 bits (w_deq)
        const float* __restrict__ bias,
        float* __restrict__ C,
        int M, int N, int K) {
    __shared__ unsigned short sA[2][2][128 * BK];
    __shared__ unsigned short sB[2][2][128 * BK];

    const int t  = threadIdx.x;
    const int w  = t >> 6;
    const int ln = t & 63;
    const int lr = ln & 15;
    const int lk = ln >> 4;
    const int wr = w >> 2;
    const int wc = w & 3;
    const int bcol = (wc >> 1) * 64 + (wc & 1) * 32;

    // T1: bijective XCD swizzle (gridDim.x % 8 == 0 here)
    const int nbn = N / BN;
    const int bid = blockIdx.x;
    const int swz = ((int)gridDim.x & 7) ? bid
                  : ((bid & 7) * ((int)gridDim.x >> 3) + (bid >> 3));
    const int m0 = (swz / nbn) * BM;
    const int n0 = (swz % nbn) * BN;

    const unsigned short* gA = A + (size_t)m0 * K;
    const unsigned short* gB = B + (size_t)n0 * K;

    const int srow   = t >> 3;
    const int brow   = (srow & 31) + ((srow >> 5) << 6);
    const int schunk = (((t & 7) ^ (srow & 7)) << 3);
    const int sldso  = (w * 8) * BK;

    const int sw = (lr & 7) << 3;
    const int e0 = (lk * 8) ^ sw;
    const int e1 = (32 + lk * 8) ^ sw;

    f32x4 acc[8][4];
#pragma unroll
    for (int i = 0; i < 8; ++i)
#pragma unroll
        for (int j = 0; j < 4; ++j)
            acc[i][j] = (f32x4)(0.0f);

    const int NT = K / BK;   // even
    const int J  = NT / 2;

    bf16x8 a0f[4][2], a1f[4][2], b0f[2][2], b1f[2][2];

    // prologue: buf0 = tile0 (4 halves), then buf1.h0 = tile1
    STAGE_A(0, 0, 0);
    STAGE_B(0, 0, 0);
    STAGE_A(0, 1, 0);
    STAGE_B(0, 1, 0);
    STAGE_A(1, 0, BK);
    STAGE_B(1, 0, BK);
    VM_(4);            // buf0 complete; buf1.h0 pair stays in flight
    BAR_();

    for (int it = 0; it < J; ++it) {
        const int t0 = 2 * it;
        const int k1 = (t0 + 1) * BK;
        int k2 = (t0 + 2) * BK;  if (k2 >= K) k2 = 0;   // clamped: dead data
        int k3 = (t0 + 3) * BK;  if (k3 >= K) k3 = 0;

        // ph1: read a0,b0 (buf0.h0); stage buf1.Ah1[t0+1]; Q00
        PHASE(READ_A(a0f, 0, 0); READ_B(b0f, 0, 0),
              STAGE_A(1, 1, k1), 0, 0, a0f, b0f, LGKM_(8), );
        // ph2: read a1 (buf0.h1); stage buf1.Bh1[t0+1]; Q10
        PHASE(READ_A(a1f, 0, 1),
              STAGE_B(1, 1, k1), 1, 0, a1f, b0f, , );
        // ph3: read b1 (buf0.h1); stage buf0.Ah0[t0+2]; Q11
        PHASE(READ_B(b1f, 0, 1),
              STAGE_A(0, 0, k2), 1, 1, a1f, b1f, , );
        // ph4: stage buf0.Bh0[t0+2]; Q01; counted gate
        PHASE(, STAGE_B(0, 0, k2), 0, 1, a0f, b1f, , VM_(4));

        // ph5-8: mirror on buf1
        PHASE(READ_A(a0f, 1, 0); READ_B(b0f, 1, 0),
              STAGE_A(0, 1, k2), 0, 0, a0f, b0f, LGKM_(8), );
        PHASE(READ_A(a1f, 1, 1),
              STAGE_B(0, 1, k2), 1, 0, a1f, b0f, , );
        PHASE(READ_B(b1f, 1, 1),
              STAGE_A(1, 0, k3), 1, 1, a1f, b1f, , );
        PHASE(, STAGE_B(1, 0, k3), 0, 1, a0f, b1f, , VM_(4));
    }
    VM_(0);   // drain clamped tail stages before exit

    // epilogue: C/D layout col = lane&15, row = (lane>>4)*4 + reg
#pragma unroll
    for (int j = 0; j < 4; ++j) {
        const int n = n0 + wc * 64 + (j >> 1) * 32 + (j & 1) * 16 + lr;
        const float bv = bias[n];
#pragma unroll
        for (int i = 0; i < 8; ++i) {
            const int m = m0 + wr * 128 + (i >> 2) * 64 + (i & 3) * 16 + lk * 4;
            f32x4 v = acc[i][j];
            C[(size_t)(m + 0) * N + n] = v[0] + bv;
            C[(size_t)(m + 1) * N + n] = v[1] + bv;
            C[(size_t)(m + 2) * N + n] = v[2] + bv;
            C[(size_t)(m + 3) * N + n] = v[3] + bv;
        }
    }
}

// ---------- launcher ----------
extern "C" void kernel_launch(void* const* d_in, const int* in_sizes, int n_in,
                              void* d_out, int out_size, void* d_ws, size_t ws_size,
                              hipStream_t stream) {
    const float* x    = (const float*)d_in[0];
    const float* wgt  = (const float*)d_in[1];
    const float* bias = (const float*)d_in[2];
    float* out        = (float*)d_out;

    const int dout = in_sizes[2];            // 4096
    const int din  = in_sizes[1] / dout;     // 4096
    const int M    = in_sizes[0] / din;      // 8192
    const int N    = dout, K = din;

    unsigned short* xb = (unsigned short*)d_ws;          // [M][K] bf16 bits
    unsigned short* wb = xb + (size_t)M * K;             // [N][K] bf16 bits

    const int ng_w = (N * K) / 8;
    qdq_weight<<<(ng_w + 255) / 256, 256, 0, stream>>>(wgt, wb, ng_w);

    const int n8_x = (M * K) / 8;
    cvt_bf16<<<(n8_x + 255) / 256, 256, 0, stream>>>(x, xb, n8_x);

    const int nwg = (M / BM) * (N / BN);     // 512, % 8 == 0
    gemm256<<<nwg, 512, 0, stream>>>(xb, wb, bias, out, M, N, K);
}

// Round 14
// 295.972 us; speedup vs baseline: 8.7276x; 1.0059x over previous
//
#include <hip/hip_runtime.h>
#include <hip/hip_bf16.h>
#include <stdint.h>

// ---------- types ----------
typedef __attribute__((ext_vector_type(8))) __bf16 bf16x8;
typedef __attribute__((ext_vector_type(4))) float f32x4;
typedef __attribute__((ext_vector_type(8))) unsigned short ushort8;

typedef const void __attribute__((address_space(1))) gv_t;
typedef void __attribute__((address_space(3))) lv_t;

#define GL16(g, l) __builtin_amdgcn_global_load_lds((gv_t*)(g), (lv_t*)(l), 16, 0, 0)

// f32 -> bf16 bits, round-to-nearest-even
__device__ __forceinline__ unsigned short f2bf(float f) {
    unsigned int u = __float_as_uint(f);
    u += 0x7fffu + ((u >> 16) & 1u);
    return (unsigned short)(u >> 16);
}

// ---------- kernel 1: per-group int4 quant-dequant of W -> bf16 bits ----------
__global__ void __launch_bounds__(256) qdq_weight(const float* __restrict__ w,
                                                  unsigned short* __restrict__ wb,
                                                  int n_groups) {
    int g = blockIdx.x * 256 + threadIdx.x;
    if (g >= n_groups) return;
    const float4* p = (const float4*)w + (size_t)g * 2;
    float4 v0 = p[0], v1 = p[1];
    float t[8] = {v0.x, v0.y, v0.z, v0.w, v1.x, v1.y, v1.z, v1.w};
    float amax = 0.0f;
#pragma unroll
    for (int j = 0; j < 8; ++j) amax = fmaxf(amax, fabsf(t[j]));
    float scale = fmaxf(amax / 7.0f, 1e-8f);
    ushort8 o;
#pragma unroll
    for (int j = 0; j < 8; ++j) {
        float q = rintf(t[j] / scale);
        q = fminf(fmaxf(q, -7.0f), 7.0f);
        o[j] = f2bf(q * scale);
    }
    *((ushort8*)wb + g) = o;
}

// ---------- kernel 2: f32 -> bf16 cast of x ----------
__global__ void __launch_bounds__(256) cvt_bf16(const float* __restrict__ x,
                                                unsigned short* __restrict__ xb,
                                                int n8) {
    int i = blockIdx.x * 256 + threadIdx.x;
    if (i >= n8) return;
    const float4* p = (const float4*)x + (size_t)i * 2;
    float4 v0 = p[0], v1 = p[1];
    ushort8 o;
    o[0] = f2bf(v0.x); o[1] = f2bf(v0.y); o[2] = f2bf(v0.z); o[3] = f2bf(v0.w);
    o[4] = f2bf(v1.x); o[5] = f2bf(v1.y); o[6] = f2bf(v1.z); o[7] = f2bf(v1.w);
    *((ushort8*)xb + i) = o;
}

// ---------- kernel 3: 256x256 8-wave UNIFORM 8-phase bf16 GEMM ----------------
// m201-exact interleave: reads one phase AHEAD of use, spread {4,8,8,4,...};
// ONE half-tile staged EVERY phase, 3 half-tiles deep, vmcnt(6) at p4/p8.
// Quadrant order per tile: Q00, Q01, Q10, Q11. Single register set (liveness
// audited: each array's refill lands exactly one phase after its last use).
#define BM 256
#define BN 256
#define BK 64

#define MFMA_Q(qm, qn, AF, BF)                                                 \
    __builtin_amdgcn_s_setprio(1);                                             \
    _Pragma("unroll")                                                          \
    for (int mi = 0; mi < 4; ++mi)                                             \
        _Pragma("unroll")                                                      \
        for (int ni = 0; ni < 2; ++ni)                                         \
            _Pragma("unroll")                                                  \
            for (int ks = 0; ks < 2; ++ks)                                     \
                acc[(qm) * 4 + mi][(qn) * 2 + ni] =                            \
                    __builtin_amdgcn_mfma_f32_16x16x32_bf16(                   \
                        AF[mi][ks], BF[ni][ks],                                \
                        acc[(qm) * 4 + mi][(qn) * 2 + ni], 0, 0, 0);           \
    __builtin_amdgcn_s_setprio(0);

#define STAGE_A(b, h, kk)                                                      \
    {                                                                          \
        GL16(gA + (size_t)((h) * 64 + srow) * K + (kk) + schunk,               \
             &sA[b][h][0] + sldso);                                            \
        GL16(gA + (size_t)((h) * 64 + 128 + srow) * K + (kk) + schunk,         \
             &sA[b][h][64 * BK] + sldso);                                      \
    }
#define STAGE_B(b, h, kk)                                                      \
    {                                                                          \
        GL16(gB + (size_t)((h) * 32 + brow) * K + (kk) + schunk,               \
             &sB[b][h][0] + sldso);                                            \
        GL16(gB + (size_t)((h) * 32 + 128 + brow) * K + (kk) + schunk,         \
             &sB[b][h][64 * BK] + sldso);                                      \
    }

#define READ_A(dst, b, h)                                                      \
    _Pragma("unroll")                                                          \
    for (int mi = 0; mi < 4; ++mi) {                                           \
        const int s_ = (wr * 64 + mi * 16 + lr) * BK;                          \
        dst[mi][0] = *(const bf16x8*)&sA[b][h][s_ + e0];                       \
        dst[mi][1] = *(const bf16x8*)&sA[b][h][s_ + e1];                       \
    }
#define READ_B(dst, b, h)                                                      \
    _Pragma("unroll")                                                          \
    for (int ni = 0; ni < 2; ++ni) {                                           \
        const int s_ = (bcol + ni * 16 + lr) * BK;                             \
        dst[ni][0] = *(const bf16x8*)&sB[b][h][s_ + e0];                       \
        dst[ni][1] = *(const bf16x8*)&sB[b][h][s_ + e1];                       \
    }

#define BAR_()     asm volatile("s_barrier" ::: "memory")
#define VM_(n)     asm volatile("s_waitcnt vmcnt(" #n ")" ::: "memory")
#define LGKM_(n)   asm volatile("s_waitcnt lgkmcnt(" #n ")" ::: "memory")
#define SCHEDBAR() __builtin_amdgcn_sched_barrier(0)

// phase: {reads(next-use) | 1 half stage ; barrier ; lgkm0 ; schedbar ;
//         16 MFMA ; [VM(6) at p4/p8] ; barrier}
#define PHASE(RDS, STG, QM, QN, AF, BF, VMQ)                                   \
    {                                                                          \
        RDS;                                                                   \
        STG;                                                                   \
        BAR_();                                                                \
        LGKM_(0);                                                              \
        SCHEDBAR();                                                            \
        MFMA_Q(QM, QN, AF, BF);                                                \
        VMQ;                                                                   \
        BAR_();                                                                \
    }

__global__ void __launch_bounds__(512, 2)
gemm256(const unsigned short* __restrict__ A,   // [M][K] bf16 bits (x)
        const unsigned short* __restrict__ B,   // [N][K] bf16 bits (w_deq)
        const float* __restrict__ bias,
        float* __restrict__ C,
        int M, int N, int K) {
    __shared__ unsigned short sA[2][2][128 * BK];
    __shared__ unsigned short sB[2][2][128 * BK];

    const int t  = threadIdx.x;
    const int w  = t >> 6;
    const int ln = t & 63;
    const int lr = ln & 15;
    const int lk = ln >> 4;
    const int wr = w >> 2;
    const int wc = w & 3;
    const int bcol = (wc >> 1) * 64 + (wc & 1) * 32;

    // T1: bijective XCD swizzle (gridDim.x % 8 == 0 here)
    const int nbn = N / BN;
    const int bid = blockIdx.x;
    const int swz = ((int)gridDim.x & 7) ? bid
                  : ((bid & 7) * ((int)gridDim.x >> 3) + (bid >> 3));
    const int m0 = (swz / nbn) * BM;
    const int n0 = (swz % nbn) * BN;

    const unsigned short* gA = A + (size_t)m0 * K;
    const unsigned short* gB = B + (size_t)n0 * K;

    const int srow   = t >> 3;
    const int brow   = (srow & 31) + ((srow >> 5) << 6);
    const int schunk = (((t & 7) ^ (srow & 7)) << 3);
    const int sldso  = (w * 8) * BK;

    const int sw = (lr & 7) << 3;
    const int e0 = (lk * 8) ^ sw;
    const int e1 = (32 + lk * 8) ^ sw;

    f32x4 acc[8][4];
#pragma unroll
    for (int i = 0; i < 8; ++i)
#pragma unroll
        for (int j = 0; j < 4; ++j)
            acc[i][j] = (f32x4)(0.0f);

    const int NT = K / BK;   // 64, even
    const int J  = NT / 2;

    bf16x8 a0f[4][2], a1f[4][2], b0f[2][2], b1f[2][2];

    // prologue: tile0 -> buf0 (4 halves), tile1 -> buf1 (4 halves); full drain
    STAGE_A(0, 0, 0);  STAGE_B(0, 0, 0);
    STAGE_B(0, 1, 0);  STAGE_A(0, 1, 0);
    STAGE_A(1, 0, BK); STAGE_B(1, 0, BK);
    STAGE_B(1, 1, BK); STAGE_A(1, 1, BK);
    VM_(0);
    BAR_();
    // pre-read tile0's A0/B0 (the "prev p7/p8" reads of the steady state)
    READ_A(a0f, 0, 0);
    READ_B(b0f, 0, 0);
    LGKM_(0);
    BAR_();
    // pre-stage buf0.Ah0 <- tile2 (the "prev p8" stage of the steady state)
    STAGE_A(0, 0, 2 * BK);

    for (int it = 0; it < J; ++it) {
        const int T = 2 * it;
        int kT2 = (T + 2) * BK;  if (kT2 >= K) kT2 = 0;   // clamped: dead data
        int kT3 = (T + 3) * BK;  if (kT3 >= K) kT3 = 0;
        int kT4 = (T + 4) * BK;  if (kT4 >= K) kT4 = 0;

        // p1: read T.B1 ; stage buf0.Bh0<-T+2 ; Q00(a0,b0)
        PHASE(READ_B(b1f, 0, 1), STAGE_B(0, 0, kT2), 0, 0, a0f, b0f, );
        // p2: read T.A1 ; stage buf0.Bh1<-T+2 ; Q01(a0,b1)
        PHASE(READ_A(a1f, 0, 1), STAGE_B(0, 1, kT2), 0, 1, a0f, b1f, );
        // p3: read T+1.A0 ; stage buf0.Ah1<-T+2 ; Q10(a1,b0)
        PHASE(READ_A(a0f, 1, 0), STAGE_A(0, 1, kT2), 1, 0, a1f, b0f, );
        // p4: read T+1.B0 ; stage buf1.Ah0<-T+3 ; Q11(a1,b1) ; VM(6)
        PHASE(READ_B(b0f, 1, 0), STAGE_A(1, 0, kT3), 1, 1, a1f, b1f, VM_(6));
        // p5: read T+1.B1 ; stage buf1.Bh0<-T+3 ; Q00'(a0,b0)
        PHASE(READ_B(b1f, 1, 1), STAGE_B(1, 0, kT3), 0, 0, a0f, b0f, );
        // p6: read T+1.A1 ; stage buf1.Bh1<-T+3 ; Q01'(a0,b1)
        PHASE(READ_A(a1f, 1, 1), STAGE_B(1, 1, kT3), 0, 1, a0f, b1f, );
        // p7: read T+2.A0 ; stage buf1.Ah1<-T+3 ; Q10'(a1,b0)
        PHASE(READ_A(a0f, 0, 0), STAGE_A(1, 1, kT3), 1, 0, a1f, b0f, );
        // p8: read T+2.B0 ; stage buf0.Ah0<-T+4 ; Q11'(a1,b1) ; VM(6)
        PHASE(READ_B(b0f, 0, 0), STAGE_A(0, 0, kT4), 1, 1, a1f, b1f, VM_(6));
    }
    VM_(0);   // drain clamped tail stages before exit

    // epilogue: C/D layout col = lane&15, row = (lane>>4)*4 + reg
#pragma unroll
    for (int j = 0; j < 4; ++j) {
        const int n = n0 + wc * 64 + (j >> 1) * 32 + (j & 1) * 16 + lr;
        const float bv = bias[n];
#pragma unroll
        for (int i = 0; i < 8; ++i) {
            const int m = m0 + wr * 128 + (i >> 2) * 64 + (i & 3) * 16 + lk * 4;
            f32x4 v = acc[i][j];
            C[(size_t)(m + 0) * N + n] = v[0] + bv;
            C[(size_t)(m + 1) * N + n] = v[1] + bv;
            C[(size_t)(m + 2) * N + n] = v[2] + bv;
            C[(size_t)(m + 3) * N + n] = v[3] + bv;
        }
    }
}

// ---------- launcher ----------
extern "C" void kernel_launch(void* const* d_in, const int* in_sizes, int n_in,
                              void* d_out, int out_size, void* d_ws, size_t ws_size,
                              hipStream_t stream) {
    const float* x    = (const float*)d_in[0];
    const float* wgt  = (const float*)d_in[1];
    const float* bias = (const float*)d_in[2];
    float* out        = (float*)d_out;

    const int dout = in_sizes[2];            // 4096
    const int din  = in_sizes[1] / dout;     // 4096
    const int M    = in_sizes[0] / din;      // 8192
    const int N    = dout, K = din;

    unsigned short* xb = (unsigned short*)d_ws;          // [M][K] bf16 bits
    unsigned short* wb = xb + (size_t)M * K;             // [N][K] bf16 bits

    const int ng_w = (N * K) / 8;
    qdq_weight<<<(ng_w + 255) / 256, 256, 0, stream>>>(wgt, wb, ng_w);

    const int n8_x = (M * K) / 8;
    cvt_bf16<<<(n8_x + 255) / 256, 256, 0, stream>>>(x, xb, n8_x);

    const int nwg = (M / BM) * (N / BN);     // 512, % 8 == 0
    gemm256<<<nwg, 512, 0, stream>>>(xb, wb, bias, out, M, N, K);
}